// Round 12
// baseline (1051.590 us; speedup 1.0000x reference)
//
#include <hip/hip_runtime.h>
#include <math.h>

#define N_NODES 100000
#define N_PAD   100032          // 3126 * 32
#define N_EDGES 1600000
#define F_IN    92
#define H_DIM   128
#define STEPS   6
#define G_GRAPHS 256
#define TH3     384
#define SSTR    136             // LDS tile row stride (ushorts): 272B = 17*16B, b128-aligned
#define HSTR    132             // LDS hn-tile row stride (floats): 2-way bank alias max
#define FPASS   8               // fill locality passes (dst ranges)
#define FRANGE  12500           // nodes per pass (8*12500 = 100000 exact)
#define EIDX_CAP 1024           // staged edge-index capacity (block mean 512, sd ~23)
#define JT      8               // fuse_w j-tile

typedef __attribute__((ext_vector_type(8))) short bf16x8;
typedef __attribute__((ext_vector_type(4))) float f32x4;

__device__ __forceinline__ unsigned short f2bf(float x) {   // fp32 -> bf16 RNE
    unsigned u = __float_as_uint(x);
    return (unsigned short)((u + 0x7fffu + ((u >> 16) & 1u)) >> 16);
}
__device__ __forceinline__ float bf2f(unsigned short h) {
    return __uint_as_float(((unsigned)h) << 16);
}

// ---------------- precompute: M2[i][j][k] = sum_c Wm[i][k][c] * w_ih[j][c] (col-major) ----
// J-tiled: one block computes JT j's for one (i) -> Wm slice read once per JT j's
// (traffic 147 MB -> ~18 MB vs the j-per-block version).
__global__ void fuse_w_kernel(const float* __restrict__ Wm, const float* __restrict__ w_ih,
                              float* __restrict__ M2) {
    int ij = blockIdx.x;            // STEPS * (TH3/JT) = 6*48 = 288 blocks
    int i  = ij / (TH3 / JT);
    int j0 = (ij % (TH3 / JT)) * JT;
    int k  = threadIdx.x;           // 128 threads
    __shared__ float wj[JT][H_DIM];
    for (int idx = k; idx < JT * H_DIM; idx += H_DIM) {
        int jj = idx >> 7, c = idx & 127;
        wj[jj][c] = w_ih[(size_t)(j0 + jj) * H_DIM + c];
    }
    __syncthreads();
    const float4* wr4 = (const float4*)(Wm + ((size_t)i * H_DIM + k) * H_DIM);
    float acc[JT];
    #pragma unroll
    for (int jj = 0; jj < JT; ++jj) acc[jj] = 0.f;
    for (int c4 = 0; c4 < H_DIM / 4; ++c4) {
        float4 wv = wr4[c4];
        int c = c4 * 4;
        #pragma unroll
        for (int jj = 0; jj < JT; ++jj) {
            acc[jj] = fmaf(wj[jj][c + 0], wv.x, acc[jj]);
            acc[jj] = fmaf(wj[jj][c + 1], wv.y, acc[jj]);
            acc[jj] = fmaf(wj[jj][c + 2], wv.z, acc[jj]);
            acc[jj] = fmaf(wj[jj][c + 3], wv.w, acc[jj]);
        }
    }
    #pragma unroll
    for (int jj = 0; jj < JT; ++jj)
        M2[((size_t)i * TH3 + j0 + jj) * H_DIM + k] = acc[jj];
}

// ---------------- pack weights into MFMA B-fragment order, split hi/lo bf16 ----------------
// fragIdx b = mg*32 + ct*4 + kc (mg = mat*3+g); element: B[k=kc*32+(lane>>4)*8+jj][j=g*128+ct*16+(lane&15)]
// mat 0..5 -> fused M step mats; mat 6 -> w_hh ([384][128] native col-major)
__global__ void pack_kernel(const float* __restrict__ M6, const float* __restrict__ w_hh,
                            unsigned short* __restrict__ PBhi, unsigned short* __restrict__ PBlo) {
    int b    = blockIdx.x;          // 672 = 21*32
    int lane = threadIdx.x;         // 64
    int kc   = b & 3;
    int ct   = (b >> 2) & 7;
    int mg   = b >> 5;              // 0..20
    int g    = mg % 3;
    int mat  = mg / 3;
    int j    = g * 128 + ct * 16 + (lane & 15);
    int k0   = kc * 32 + (lane >> 4) * 8;
    size_t outBase = ((size_t)b * 64 + lane) * 8;
    #pragma unroll
    for (int jj = 0; jj < 8; ++jj) {
        int k = k0 + jj;
        float v = (mat < 6) ? M6[((size_t)mat * TH3 + j) * H_DIM + k]
                            : w_hh[(size_t)j * H_DIM + k];
        unsigned short hv = f2bf(v);
        PBhi[outBase + jj] = hv;
        PBlo[outBase + jj] = f2bf(v - bf2f(hv));
    }
}

// ---------------- embed: h = tanh(x @ W_embed), output split bf16 hi/lo ----------------
#define ET 16
__global__ void embed_kernel(const float* __restrict__ x, const float* __restrict__ We,
                             unsigned short* __restrict__ h_hi, unsigned short* __restrict__ h_lo) {
    int n0 = blockIdx.x * ET;       // 6250 blocks, exact
    int j  = threadIdx.x;           // 128 threads
    __shared__ float xs[ET * F_IN];
    for (int i = j; i < ET * F_IN; i += H_DIM) xs[i] = x[n0 * F_IN + i];
    __syncthreads();
    float acc[ET];
    #pragma unroll
    for (int n = 0; n < ET; ++n) acc[n] = 0.f;
    const float4* xs4 = (const float4*)xs;
    for (int k4 = 0; k4 < F_IN / 4; ++k4) {
        int k = k4 * 4;
        float w0 = We[(k + 0) * H_DIM + j];
        float w1 = We[(k + 1) * H_DIM + j];
        float w2 = We[(k + 2) * H_DIM + j];
        float w3 = We[(k + 3) * H_DIM + j];
        #pragma unroll
        for (int n = 0; n < ET; ++n) {
            float4 a = xs4[n * (F_IN / 4) + k4];
            acc[n] = fmaf(a.x, w0, acc[n]);
            acc[n] = fmaf(a.y, w1, acc[n]);
            acc[n] = fmaf(a.z, w2, acc[n]);
            acc[n] = fmaf(a.w, w3, acc[n]);
        }
    }
    #pragma unroll
    for (int n = 0; n < ET; ++n) {
        float e2 = __expf(2.f * acc[n]);
        float v  = 1.f - 2.f / (e2 + 1.f);
        size_t o = (size_t)(n0 + n) * H_DIM + j;
        unsigned short hv = f2bf(v);
        h_hi[o] = hv;
        h_lo[o] = f2bf(v - bf2f(hv));
    }
}

// ---------------- CSR build: histogram -> scan -> bucket fill ----------------
__global__ void hist_kernel(const int* __restrict__ dst, int* __restrict__ count) {
    int e = blockIdx.x * 256 + threadIdx.x;
    if (e < N_EDGES) atomicAdd(&count[dst[e]], 1);
}

__global__ void scan_block_kernel(const int* __restrict__ count, int* __restrict__ offs,
                                  int* __restrict__ blockSums) {
    __shared__ int tmp[256];
    int i = blockIdx.x * 256 + threadIdx.x;
    int t = threadIdx.x;
    int v = (i < N_NODES) ? count[i] : 0;
    tmp[t] = v;
    __syncthreads();
    for (int d = 1; d < 256; d <<= 1) {
        int add = (t >= d) ? tmp[t - d] : 0;
        __syncthreads();
        tmp[t] += add;
        __syncthreads();
    }
    if (i < N_NODES) offs[i] = tmp[t] - v;
    if (t == 255) blockSums[blockIdx.x] = tmp[255];
}

__global__ void scan_sums_kernel(int* __restrict__ blockSums, int nb) {  // 1 block, 512 thr
    __shared__ int tmp[512];
    int t = threadIdx.x;
    int v = (t < nb) ? blockSums[t] : 0;
    tmp[t] = v;
    __syncthreads();
    for (int d = 1; d < 512; d <<= 1) {
        int add = (t >= d) ? tmp[t - d] : 0;
        __syncthreads();
        tmp[t] += add;
        __syncthreads();
    }
    if (t < nb) blockSums[t] = tmp[t] - v;
}

__global__ void scan_add_kernel(int* __restrict__ offs, const int* __restrict__ blockSums) {
    int i = blockIdx.x * 256 + threadIdx.x;
    if (i < N_NODES) offs[i] += blockSums[blockIdx.x];
    if (i == 0) offs[N_NODES] = N_EDGES;
}

// fill with temporal-locality passes (writes confined to ~0.8 MB L2-resident slices)
__global__ void fill_kernel(const int* __restrict__ src, const int* __restrict__ dst,
                            const int* __restrict__ offs, int* __restrict__ cursor,
                            int* __restrict__ srcSorted) {
    int e = blockIdx.x * 256 + threadIdx.x;
    if (e >= N_EDGES) return;
    for (int p = 0; p < FPASS; ++p) {
        int lo = p * FRANGE;
        int d = dst[e];
        if (d >= lo && d < lo + FRANGE) {
            int pos = atomicAdd(&cursor[d], 1);
            srcSorted[offs[d] + pos] = src[e];
        }
    }
}

// ---------------- fused gather + GRU step via MFMA ----------------
// Block = 8 waves = 32 rows x 128 ch. Phases (R7-verified structure):
//   0: stage own h rows (hi+lo) to LDS; coop-stage block's CSR index span
//   1: gather s = sum h_hi_in[src]; 16 ch x half-list per thread; 2-edge x 2-chunk
//      batches (4 x 16B lines in flight); indices from LDS. acc NOT live during
//      gather (R10 lesson: acc live across gather -> scratch spill).
//   2: h-side MFMAs; 3: sync; s-side MFMAs; 4: GRU epilogue.
// LAST STEP (matI==STEPS-1): global h stores are DEAD (only pooling consumed
// them) -> skip 51.2 MB of stores and fuse the graph-mean pooling here:
// per-channel segmented sum over the block's 32 hnF rows (batch sorted ->
// contiguous runs; pad rows only in final block tail) + atomicAdd partials.
// Races: gather reads arbitrary h_hi_in rows -> h_hi ping-pongs across steps.
__global__ __launch_bounds__(512, 4) void gru_fused_kernel(
    const unsigned short* __restrict__ h_hi_in,
    unsigned short* __restrict__ h_hi_out,
    unsigned short* __restrict__ h_lo,
    const int* __restrict__ offs, const int* __restrict__ srcS,
    const unsigned short* __restrict__ PBhi, const unsigned short* __restrict__ PBlo,
    int matI, const float* __restrict__ b_ih, const float* __restrict__ b_hh,
    const int* __restrict__ batch, float* __restrict__ pooled)
{
    __shared__ __align__(16) unsigned short buf[3 * 32 * SSTR];   // 26.1 KB
    __shared__ int eIdx[EIDX_CAP];                                // 4 KB staged indices
    unsigned short* sHh = buf;                  // h_hi tile (32 rows)
    unsigned short* sHl = buf + 32 * SSTR;      // h_lo tile
    unsigned short* sS  = buf + 2 * 32 * SSTR;  // gathered s tile (bf16)
    float* hnF = (float*)buf;                   // epilogue reuse: 32*HSTR fp32 (16.9 KB)

    int nt = blockIdx.x;            // 3126
    int rowBase = nt * 32;
    int t = threadIdx.x;            // 512
    int row = t >> 4;               // 0..31
    int node = rowBase + row;

    // hoisted CSR bounds: in flight alongside the staging loads below
    int beg = 0, end = 0;
    if (node < N_NODES) { beg = offs[node]; end = offs[node + 1]; }
    int eBegBlk = offs[rowBase < N_NODES ? rowBase : N_NODES];
    int eEndBlk = offs[(rowBase + 32) < N_NODES ? (rowBase + 32) : N_NODES];
    int eCnt = eEndBlk - eBegBlk;

    // phase 0: stage h tiles (1 chunk/thread) + block's edge indices (coalesced)
    {
        int c8 = (t & 15) * 8;
        size_t g = (size_t)node * H_DIM + c8;
        int l = row * SSTR + c8;
        *(bf16x8*)&sHh[l] = *(const bf16x8*)(h_hi_in + g);
        *(bf16x8*)&sHl[l] = *(const bf16x8*)(h_lo + g);
    }
    {
        int lim = eCnt < EIDX_CAP ? eCnt : EIDX_CAP;
        for (int k = t; k < lim; k += 512) eIdx[k] = srcS[eBegBlk + k];
    }
    __syncthreads();

    // phase 1: gather — 16 channels (2 chunks) per thread over half the edge list.
    // R2's proven batch: 2 edges x 2 chunks = 4 independent 16B loads in flight;
    // whole next batch prefetched at one point, guarded by i+4 <= hi.
    {
        int sub   = t & 15;
        int halfI = sub >> 3;                  // which half of the edge list
        int cOff  = (sub & 7) * 16;            // 16-channel group (ushort offset)
        float a[16];
        #pragma unroll
        for (int j = 0; j < 16; ++j) a[j] = 0.f;
        if (node < N_NODES) {
            int len = end - beg;
            int h0  = (len + 1) >> 1;
            int lo  = beg + (halfI ? h0 : 0);
            int hi  = halfI ? end : beg + h0;
            const unsigned short* hb = h_hi_in + cOff;

            auto gatherRun = [&](auto IDXF) {
                int i = lo;
                int n0 = 0, n1 = 0, n2 = 0, n3 = 0;
                bool have4 = (i + 4 <= hi);
                if (have4) { n0 = IDXF(i); n1 = IDXF(i+1); n2 = IDXF(i+2); n3 = IDXF(i+3); }
                while (have4) {
                    const bf16x8* p0 = (const bf16x8*)(hb + (size_t)n0 * H_DIM);
                    const bf16x8* p1 = (const bf16x8*)(hb + (size_t)n1 * H_DIM);
                    const bf16x8* p2 = (const bf16x8*)(hb + (size_t)n2 * H_DIM);
                    const bf16x8* p3 = (const bf16x8*)(hb + (size_t)n3 * H_DIM);
                    bf16x8 v0a = p0[0], v0b = p0[1];
                    bf16x8 v1a = p1[0], v1b = p1[1];
                    bf16x8 v2a = p2[0], v2b = p2[1];
                    bf16x8 v3a = p3[0], v3b = p3[1];
                    i += 4;
                    have4 = (i + 4 <= hi);
                    if (have4) { n0 = IDXF(i); n1 = IDXF(i+1); n2 = IDXF(i+2); n3 = IDXF(i+3); }
                    #pragma unroll
                    for (int j = 0; j < 8; ++j) {
                        a[j]     += (bf2f((unsigned short)v0a[j]) + bf2f((unsigned short)v1a[j]))
                                  + (bf2f((unsigned short)v2a[j]) + bf2f((unsigned short)v3a[j]));
                        a[8 + j] += (bf2f((unsigned short)v0b[j]) + bf2f((unsigned short)v1b[j]))
                                  + (bf2f((unsigned short)v2b[j]) + bf2f((unsigned short)v3b[j]));
                    }
                }
                if (i + 2 <= hi) {
                    int q0 = IDXF(i), q1 = IDXF(i + 1);
                    const bf16x8* p0 = (const bf16x8*)(hb + (size_t)q0 * H_DIM);
                    const bf16x8* p1 = (const bf16x8*)(hb + (size_t)q1 * H_DIM);
                    bf16x8 v0a = p0[0], v0b = p0[1];
                    bf16x8 v1a = p1[0], v1b = p1[1];
                    #pragma unroll
                    for (int j = 0; j < 8; ++j) {
                        a[j]     += bf2f((unsigned short)v0a[j]) + bf2f((unsigned short)v1a[j]);
                        a[8 + j] += bf2f((unsigned short)v0b[j]) + bf2f((unsigned short)v1b[j]);
                    }
                    i += 2;
                }
                if (i < hi) {
                    int q0 = IDXF(i);
                    const bf16x8* p = (const bf16x8*)(hb + (size_t)q0 * H_DIM);
                    bf16x8 va = p[0], vb = p[1];
                    #pragma unroll
                    for (int j = 0; j < 8; ++j) {
                        a[j]     += bf2f((unsigned short)va[j]);
                        a[8 + j] += bf2f((unsigned short)vb[j]);
                    }
                }
            };

            if (eCnt <= EIDX_CAP) {
                int eb = eBegBlk;
                gatherRun([&](int x) { return eIdx[x - eb]; });
            } else {
                gatherRun([&](int x) { return srcS[x]; });
            }
        }
        // combine the two half-list partials (partner lane differs in bit 3 -> same wave)
        #pragma unroll
        for (int j = 0; j < 16; ++j) a[j] += __shfl_xor(a[j], 8);
        bf16x8 o;
        #pragma unroll
        for (int j = 0; j < 8; ++j) o[j] = (short)f2bf(a[halfI * 8 + j]);
        *(bf16x8*)&sS[row * SSTR + cOff + halfI * 8] = o;   // own slot; published by next sync
    }

    int lane = t & 63;
    int ct   = t >> 6;              // wave id = channel tile 0..7
    int rloc = lane & 15;
    int kOff = (lane >> 4) * 8;

    f32x4 accRZ[2][2], accIn[2], accHn[2];   // merged r,z; split n  (32 regs)
    #pragma unroll
    for (int rs = 0; rs < 2; ++rs) {
        accRZ[0][rs] = (f32x4){0.f, 0.f, 0.f, 0.f};
        accRZ[1][rs] = (f32x4){0.f, 0.f, 0.f, 0.f};
        accIn[rs]    = (f32x4){0.f, 0.f, 0.f, 0.f};
        accHn[rs]    = (f32x4){0.f, 0.f, 0.f, 0.f};
    }

    // phase 2: h-side MFMAs — independent of other threads' gather results
    for (int kc = 0; kc < 4; ++kc) {
        int aOff = kc * 32 + kOff;
        bf16x8 aHh4[2], aHl4[2];
        #pragma unroll
        for (int rs = 0; rs < 2; ++rs) {
            int al = (rs * 16 + rloc) * SSTR + aOff;
            aHh4[rs] = *(const bf16x8*)(&sHh[al]);
            aHl4[rs] = *(const bf16x8*)(&sHl[al]);
        }
        #pragma unroll
        for (int g = 0; g < 3; ++g) {
            size_t oH = ((size_t)((18 + g) * 32 + ct * 4 + kc) * 64 + lane) * 8;
            bf16x8 bHh = *(const bf16x8*)(PBhi + oH);
            bf16x8 bHl = *(const bf16x8*)(PBlo + oH);
            #pragma unroll
            for (int rs = 0; rs < 2; ++rs) {
                f32x4* tH = (g == 0) ? &accRZ[0][rs] : (g == 1) ? &accRZ[1][rs] : &accHn[rs];
                *tH = __builtin_amdgcn_mfma_f32_16x16x32_bf16(aHh4[rs], bHh, *tH, 0, 0, 0);
                *tH = __builtin_amdgcn_mfma_f32_16x16x32_bf16(aHl4[rs], bHh, *tH, 0, 0, 0);
                *tH = __builtin_amdgcn_mfma_f32_16x16x32_bf16(aHh4[rs], bHl, *tH, 0, 0, 0);
            }
        }
    }

    __syncthreads();    // gathered s tile complete

    // phase 3: s-side MFMAs from LDS
    const int fI0 = matI * 3;
    for (int kc = 0; kc < 4; ++kc) {
        int aOff = kc * 32 + kOff;
        bf16x8 aS[2];
        #pragma unroll
        for (int rs = 0; rs < 2; ++rs)
            aS[rs] = *(const bf16x8*)(&sS[(rs * 16 + rloc) * SSTR + aOff]);
        #pragma unroll
        for (int g = 0; g < 3; ++g) {
            size_t oI = ((size_t)((fI0 + g) * 32 + ct * 4 + kc) * 64 + lane) * 8;
            bf16x8 bIh = *(const bf16x8*)(PBhi + oI);
            bf16x8 bIl = *(const bf16x8*)(PBlo + oI);
            #pragma unroll
            for (int rs = 0; rs < 2; ++rs) {
                f32x4* tI = (g == 0) ? &accRZ[0][rs] : (g == 1) ? &accRZ[1][rs] : &accIn[rs];
                *tI = __builtin_amdgcn_mfma_f32_16x16x32_bf16(aS[rs], bIh, *tI, 0, 0, 0);
                *tI = __builtin_amdgcn_mfma_f32_16x16x32_bf16(aS[rs], bIl, *tI, 0, 0, 0);
            }
        }
    }

    // ---- epilogue: thread-local GRU for all 8 values, then single LDS round-trip ----
    int c = ct * 16 + rloc;
    float br  = b_ih[c] + b_hh[c];               // merged r bias
    float bz  = b_ih[128 + c] + b_hh[128 + c];   // merged z bias
    float bin = b_ih[256 + c], bhn = b_hh[256 + c];
    int rl = (lane >> 4) * 4;       // local row base within each 16-row subtile

    float hnv[2][4];
    #pragma unroll
    for (int rs = 0; rs < 2; ++rs) {
        #pragma unroll
        for (int r = 0; r < 4; ++r) {
            int lrow = rs * 16 + rl + r;
            float hold = bf2f(sHh[lrow * SSTR + c]) + bf2f(sHl[lrow * SSTR + c]);
            float rr = 1.f / (1.f + __expf(-(accRZ[0][rs][r] + br)));
            float zz = 1.f / (1.f + __expf(-(accRZ[1][rs][r] + bz)));
            float pre = (accIn[rs][r] + bin) + rr * (accHn[rs][r] + bhn);
            float e2 = __expf(2.f * pre);
            float cand = 1.f - 2.f / (e2 + 1.f);  // tanh, overflow-safe
            hnv[rs][r] = (1.f - zz) * cand + zz * hold;
        }
    }
    __syncthreads();                // all hold reads done; tiles now reusable
    // stage graph ids for fused pooling (last step only); eIdx is dead after gather
    int* gIds = eIdx;
    if (matI == STEPS - 1 && t < 32) {
        int gr = rowBase + t;
        gIds[t] = (gr < N_NODES) ? batch[gr] : -1;
    }
    #pragma unroll
    for (int rs = 0; rs < 2; ++rs)
        #pragma unroll
        for (int r = 0; r < 4; ++r)
            hnF[(rs * 16 + rl + r) * HSTR + c] = hnv[rs][r];   // 2-way bank alias: free
    __syncthreads();                // hn tile (+ gIds) complete

    if (matI != STEPS - 1) {
        // coop store: 32 rows x 32 float4 chunks = 1024, 512 threads x 2
        #pragma unroll
        for (int i = t; i < 32 * 32; i += 512) {
            int rw = i >> 5;
            int c4 = (i & 31) * 4;
            int gRow = rowBase + rw;
            if (gRow < N_NODES) {
                float4 v = *(const float4*)(&hnF[rw * HSTR + c4]);
                ushort4 hh, ll;
                hh.x = f2bf(v.x); ll.x = f2bf(v.x - bf2f(hh.x));
                hh.y = f2bf(v.y); ll.y = f2bf(v.y - bf2f(hh.y));
                hh.z = f2bf(v.z); ll.z = f2bf(v.z - bf2f(hh.z));
                hh.w = f2bf(v.w); ll.w = f2bf(v.w - bf2f(hh.w));
                size_t o = (size_t)gRow * H_DIM + c4;
                *(ushort4*)(h_hi_out + o) = hh;
                *(ushort4*)(h_lo + o) = ll;
            }
        }
    } else if (t < H_DIM) {
        // fused pooling: per-channel segmented sum over 32 rows (batch sorted ->
        // runs contiguous; pad rows only in final block tail). Global h stores
        // are dead on the last step and skipped entirely.
        float acc = 0.f;
        int curG = -1;
        for (int r = 0; r < 32; ++r) {
            int g = gIds[r];                  // uniform across the 128 threads
            if (g < 0) break;                 // pad tail
            if (g != curG) {
                if (curG >= 0) atomicAdd(&pooled[curG * H_DIM + t], acc);
                acc = 0.f; curG = g;
            }
            acc += hnF[r * HSTR + t];
        }
        if (curG >= 0) atomicAdd(&pooled[curG * H_DIM + t], acc);
    }
}

// ---------------- pool phase B: normalize + relu + prediction head ----------------
__global__ void pool_head(const float* __restrict__ pooled, const int* __restrict__ batch,
                          const float* __restrict__ w_pred, const float* __restrict__ b_pred,
                          float* __restrict__ out) {
    int g = blockIdx.x;             // 256 blocks
    int t = threadIdx.x;            // 128 threads
    __shared__ int bounds[2];
    __shared__ float red[2];
    if (t < 2) {
        int target = g + t;
        int lo = 0, hi = N_NODES;
        while (lo < hi) {
            int mid = (lo + hi) >> 1;
            if (batch[mid] < target) lo = mid + 1; else hi = mid;
        }
        bounds[t] = lo;
    }
    __syncthreads();
    int cnt = bounds[1] - bounds[0];
    float pv = pooled[g * H_DIM + t] / fmaxf((float)cnt, 1.f);
    pv = fmaxf(pv, 0.f);
    float v = pv * w_pred[t];
    #pragma unroll
    for (int off = 32; off > 0; off >>= 1) v += __shfl_down(v, off);
    if ((t & 63) == 0) red[t >> 6] = v;
    __syncthreads();
    if (t == 0) out[g] = red[0] + red[1] + b_pred[0];
}

extern "C" void kernel_launch(void* const* d_in, const int* in_sizes, int n_in,
                              void* d_out, int out_size, void* d_ws, size_t ws_size,
                              hipStream_t stream) {
    const float* x      = (const float*)d_in[0];
    const int*   ei     = (const int*)d_in[1];    // [2,E]: src = ei, dst = ei+E
    const int*   batch  = (const int*)d_in[2];
    const float* We     = (const float*)d_in[3];
    const float* Wm     = (const float*)d_in[4];
    const float* w_ih   = (const float*)d_in[5];
    const float* w_hh   = (const float*)d_in[6];  // [384][128] native col-major
    const float* b_ih   = (const float*)d_in[7];
    const float* b_hh   = (const float*)d_in[8];
    const float* w_pred = (const float*)d_in[9];
    const float* b_pred = (const float*)d_in[10];
    float* out = (float*)d_out;

    const size_t HN = (size_t)N_PAD * H_DIM;
    unsigned short* h_hiA = (unsigned short*)d_ws;                 // ping
    unsigned short* h_lo  = h_hiA + HN;                            // single-buffered
    unsigned short* h_hiB = h_lo + HN;                             // pong
    float* M6 = (float*)(h_hiB + HN);                              // 6*384*128 fp32
    unsigned short* PBhi = (unsigned short*)(M6 + (size_t)STEPS * TH3 * H_DIM);
    unsigned short* PBlo = PBhi + 21 * 32 * 64 * 8;
    int* offs      = (int*)(PBlo + 21 * 32 * 64 * 8);              // N+1
    int* srcSorted = offs + (N_NODES + 1);                         // E
    float* pooled  = (float*)(srcSorted + N_EDGES);                // 256*128 fp32
    // CSR temporaries overlaid on h_hiB (first written by gru step 0, after fill)
    int* count     = (int*)h_hiB;
    int* cursor    = count + N_NODES;
    int* blockSums = cursor + N_NODES;

    const int* esrc = ei;
    const int* edst = ei + N_EDGES;
    const int EB = (N_EDGES + 255) / 256;                // 6250
    const int NB = (N_NODES + 255) / 256;                // 391

    hipMemsetAsync(count, 0, 2 * (size_t)N_NODES * sizeof(int), stream);
    hipMemsetAsync(pooled, 0, (size_t)G_GRAPHS * H_DIM * sizeof(float), stream);
    hist_kernel<<<EB, 256, 0, stream>>>(edst, count);
    scan_block_kernel<<<NB, 256, 0, stream>>>(count, offs, blockSums);
    scan_sums_kernel<<<1, 512, 0, stream>>>(blockSums, NB);
    scan_add_kernel<<<NB, 256, 0, stream>>>(offs, blockSums);
    fill_kernel<<<EB, 256, 0, stream>>>(esrc, edst, offs, cursor, srcSorted);

    fuse_w_kernel<<<STEPS * (TH3 / JT), H_DIM, 0, stream>>>(Wm, w_ih, M6);
    pack_kernel<<<21 * 32, 64, 0, stream>>>(M6, w_hh, PBhi, PBlo);
    embed_kernel<<<N_NODES / ET, H_DIM, 0, stream>>>(x, We, h_hiA, h_lo);

    for (int i = 0; i < STEPS; ++i) {
        const unsigned short* hin = (i & 1) ? h_hiB : h_hiA;
        unsigned short*       hout = (i & 1) ? h_hiA : h_hiB;
        gru_fused_kernel<<<N_PAD / 32, 512, 0, stream>>>(hin, hout, h_lo,
                                                         offs, srcSorted, PBhi, PBlo,
                                                         i, b_ih, b_hh, batch, pooled);
    }
    // pooling partials accumulated inside the last gru step

    pool_head<<<G_GRAPHS, H_DIM, 0, stream>>>(pooled, batch, w_pred, b_pred, out);
}

// Round 13
// 1024.713 us; speedup vs baseline: 1.0262x; 1.0262x over previous
//
#include <hip/hip_runtime.h>
#include <math.h>

#define N_NODES 100000
#define N_PAD   100032          // 3126 * 32
#define N_EDGES 1600000
#define F_IN    92
#define H_DIM   128
#define STEPS   6
#define G_GRAPHS 256
#define TH3     384
#define SSTR    136             // LDS tile row stride (ushorts): 272B = 17*16B, b128-aligned
#define HSTR    132             // LDS hn-tile row stride (floats): 2-way bank alias max
#define FPASS   8               // fill locality passes (dst ranges)
#define FRANGE  12500           // nodes per pass (8*12500 = 100000 exact)
#define EIDX_CAP 1024           // staged edge-index capacity (block mean 512, sd ~23)
#define JT      8               // fuse_w j-tile

typedef __attribute__((ext_vector_type(8))) short bf16x8;
typedef __attribute__((ext_vector_type(4))) float f32x4;

__device__ __forceinline__ unsigned short f2bf(float x) {   // fp32 -> bf16 RNE
    unsigned u = __float_as_uint(x);
    return (unsigned short)((u + 0x7fffu + ((u >> 16) & 1u)) >> 16);
}
__device__ __forceinline__ float bf2f(unsigned short h) {
    return __uint_as_float(((unsigned)h) << 16);
}

// ---------------- precompute: M2[i][j][k] = sum_c Wm[i][k][c] * w_ih[j][c] (col-major) ----
// J-tiled: one block computes JT j's for one (i) -> Wm slice read once per JT j's
// (traffic 147 MB -> ~18 MB vs the j-per-block version).
__global__ void fuse_w_kernel(const float* __restrict__ Wm, const float* __restrict__ w_ih,
                              float* __restrict__ M2) {
    int ij = blockIdx.x;            // STEPS * (TH3/JT) = 6*48 = 288 blocks
    int i  = ij / (TH3 / JT);
    int j0 = (ij % (TH3 / JT)) * JT;
    int k  = threadIdx.x;           // 128 threads
    __shared__ float wj[JT][H_DIM];
    for (int idx = k; idx < JT * H_DIM; idx += H_DIM) {
        int jj = idx >> 7, c = idx & 127;
        wj[jj][c] = w_ih[(size_t)(j0 + jj) * H_DIM + c];
    }
    __syncthreads();
    const float4* wr4 = (const float4*)(Wm + ((size_t)i * H_DIM + k) * H_DIM);
    float acc[JT];
    #pragma unroll
    for (int jj = 0; jj < JT; ++jj) acc[jj] = 0.f;
    for (int c4 = 0; c4 < H_DIM / 4; ++c4) {
        float4 wv = wr4[c4];
        int c = c4 * 4;
        #pragma unroll
        for (int jj = 0; jj < JT; ++jj) {
            acc[jj] = fmaf(wj[jj][c + 0], wv.x, acc[jj]);
            acc[jj] = fmaf(wj[jj][c + 1], wv.y, acc[jj]);
            acc[jj] = fmaf(wj[jj][c + 2], wv.z, acc[jj]);
            acc[jj] = fmaf(wj[jj][c + 3], wv.w, acc[jj]);
        }
    }
    #pragma unroll
    for (int jj = 0; jj < JT; ++jj)
        M2[((size_t)i * TH3 + j0 + jj) * H_DIM + k] = acc[jj];
}

// ---------------- pack weights into MFMA B-fragment order, split hi/lo bf16 ----------------
// fragIdx b = mg*32 + ct*4 + kc (mg = mat*3+g); element: B[k=kc*32+(lane>>4)*8+jj][j=g*128+ct*16+(lane&15)]
// mat 0..5 -> fused M step mats; mat 6 -> w_hh ([384][128] native col-major)
__global__ void pack_kernel(const float* __restrict__ M6, const float* __restrict__ w_hh,
                            unsigned short* __restrict__ PBhi, unsigned short* __restrict__ PBlo) {
    int b    = blockIdx.x;          // 672 = 21*32
    int lane = threadIdx.x;         // 64
    int kc   = b & 3;
    int ct   = (b >> 2) & 7;
    int mg   = b >> 5;              // 0..20
    int g    = mg % 3;
    int mat  = mg / 3;
    int j    = g * 128 + ct * 16 + (lane & 15);
    int k0   = kc * 32 + (lane >> 4) * 8;
    size_t outBase = ((size_t)b * 64 + lane) * 8;
    #pragma unroll
    for (int jj = 0; jj < 8; ++jj) {
        int k = k0 + jj;
        float v = (mat < 6) ? M6[((size_t)mat * TH3 + j) * H_DIM + k]
                            : w_hh[(size_t)j * H_DIM + k];
        unsigned short hv = f2bf(v);
        PBhi[outBase + jj] = hv;
        PBlo[outBase + jj] = f2bf(v - bf2f(hv));
    }
}

// ---------------- embed: h = tanh(x @ W_embed), output split bf16 hi/lo ----------------
#define ET 16
__global__ void embed_kernel(const float* __restrict__ x, const float* __restrict__ We,
                             unsigned short* __restrict__ h_hi, unsigned short* __restrict__ h_lo) {
    int n0 = blockIdx.x * ET;       // 6250 blocks, exact
    int j  = threadIdx.x;           // 128 threads
    __shared__ float xs[ET * F_IN];
    for (int i = j; i < ET * F_IN; i += H_DIM) xs[i] = x[n0 * F_IN + i];
    __syncthreads();
    float acc[ET];
    #pragma unroll
    for (int n = 0; n < ET; ++n) acc[n] = 0.f;
    const float4* xs4 = (const float4*)xs;
    for (int k4 = 0; k4 < F_IN / 4; ++k4) {
        int k = k4 * 4;
        float w0 = We[(k + 0) * H_DIM + j];
        float w1 = We[(k + 1) * H_DIM + j];
        float w2 = We[(k + 2) * H_DIM + j];
        float w3 = We[(k + 3) * H_DIM + j];
        #pragma unroll
        for (int n = 0; n < ET; ++n) {
            float4 a = xs4[n * (F_IN / 4) + k4];
            acc[n] = fmaf(a.x, w0, acc[n]);
            acc[n] = fmaf(a.y, w1, acc[n]);
            acc[n] = fmaf(a.z, w2, acc[n]);
            acc[n] = fmaf(a.w, w3, acc[n]);
        }
    }
    #pragma unroll
    for (int n = 0; n < ET; ++n) {
        float e2 = __expf(2.f * acc[n]);
        float v  = 1.f - 2.f / (e2 + 1.f);
        size_t o = (size_t)(n0 + n) * H_DIM + j;
        unsigned short hv = f2bf(v);
        h_hi[o] = hv;
        h_lo[o] = f2bf(v - bf2f(hv));
    }
}

// ---------------- CSR build: histogram -> scan -> bucket fill ----------------
__global__ void hist_kernel(const int* __restrict__ dst, int* __restrict__ count) {
    int e = blockIdx.x * 256 + threadIdx.x;
    if (e < N_EDGES) atomicAdd(&count[dst[e]], 1);
}

__global__ void scan_block_kernel(const int* __restrict__ count, int* __restrict__ offs,
                                  int* __restrict__ blockSums) {
    __shared__ int tmp[256];
    int i = blockIdx.x * 256 + threadIdx.x;
    int t = threadIdx.x;
    int v = (i < N_NODES) ? count[i] : 0;
    tmp[t] = v;
    __syncthreads();
    for (int d = 1; d < 256; d <<= 1) {
        int add = (t >= d) ? tmp[t - d] : 0;
        __syncthreads();
        tmp[t] += add;
        __syncthreads();
    }
    if (i < N_NODES) offs[i] = tmp[t] - v;
    if (t == 255) blockSums[blockIdx.x] = tmp[255];
}

__global__ void scan_sums_kernel(int* __restrict__ blockSums, int nb) {  // 1 block, 512 thr
    __shared__ int tmp[512];
    int t = threadIdx.x;
    int v = (t < nb) ? blockSums[t] : 0;
    tmp[t] = v;
    __syncthreads();
    for (int d = 1; d < 512; d <<= 1) {
        int add = (t >= d) ? tmp[t - d] : 0;
        __syncthreads();
        tmp[t] += add;
        __syncthreads();
    }
    if (t < nb) blockSums[t] = tmp[t] - v;
}

__global__ void scan_add_kernel(int* __restrict__ offs, const int* __restrict__ blockSums) {
    int i = blockIdx.x * 256 + threadIdx.x;
    if (i < N_NODES) offs[i] += blockSums[blockIdx.x];
    if (i == 0) offs[N_NODES] = N_EDGES;
}

// fill with temporal-locality passes (writes confined to ~0.8 MB L2-resident slices)
__global__ void fill_kernel(const int* __restrict__ src, const int* __restrict__ dst,
                            const int* __restrict__ offs, int* __restrict__ cursor,
                            int* __restrict__ srcSorted) {
    int e = blockIdx.x * 256 + threadIdx.x;
    if (e >= N_EDGES) return;
    for (int p = 0; p < FPASS; ++p) {
        int lo = p * FRANGE;
        int d = dst[e];
        if (d >= lo && d < lo + FRANGE) {
            int pos = atomicAdd(&cursor[d], 1);
            srcSorted[offs[d] + pos] = src[e];
        }
    }
}

// ---------------- fused gather + GRU step via MFMA ----------------
// Block = 8 waves = 32 rows x 128 ch. Phases (R7-verified structure):
//   0: stage own h rows (hi+lo) to LDS; coop-stage block's CSR index span
//      (removes 8x-redundant global index loads from the gather's critical chain)
//   1: gather s = sum h_hi_in[src]; 16 ch x half-list per thread; 2-edge x 2-chunk
//      batches (4 x 16B lines in flight), whole-batch prefetch guarded by i+4<=hi;
//      indices from LDS (global fallback if >CAP). acc NOT live during gather
//      (R10 lesson: acc live across gather -> scratch spill, WRITE_SIZE 50->267MB).
//   2: h-side MFMAs (depend only on staged tile)
//   3: sync; s-side MFMAs from gathered LDS tile
//   4: GRU epilogue; write h_hi_out + h_lo (own rows only)
// Races: gather reads arbitrary h_hi_in rows -> h_hi ping-pongs across steps.
// h_lo is only touched by the owning block -> in-place single buffer.
__global__ __launch_bounds__(512, 4) void gru_fused_kernel(
    const unsigned short* __restrict__ h_hi_in,
    unsigned short* __restrict__ h_hi_out,
    unsigned short* __restrict__ h_lo,
    const int* __restrict__ offs, const int* __restrict__ srcS,
    const unsigned short* __restrict__ PBhi, const unsigned short* __restrict__ PBlo,
    int matI, const float* __restrict__ b_ih, const float* __restrict__ b_hh)
{
    __shared__ __align__(16) unsigned short buf[3 * 32 * SSTR];   // 26.1 KB
    __shared__ int eIdx[EIDX_CAP];                                // 4 KB staged indices
    unsigned short* sHh = buf;                  // h_hi tile (32 rows)
    unsigned short* sHl = buf + 32 * SSTR;      // h_lo tile
    unsigned short* sS  = buf + 2 * 32 * SSTR;  // gathered s tile (bf16)
    float* hnF = (float*)buf;                   // epilogue reuse: 32*HSTR fp32 (16.9 KB)

    int nt = blockIdx.x;            // 3126
    int rowBase = nt * 32;
    int t = threadIdx.x;            // 512
    int row = t >> 4;               // 0..31
    int node = rowBase + row;

    // hoisted CSR bounds: in flight alongside the staging loads below
    int beg = 0, end = 0;
    if (node < N_NODES) { beg = offs[node]; end = offs[node + 1]; }
    int eBegBlk = offs[rowBase < N_NODES ? rowBase : N_NODES];
    int eEndBlk = offs[(rowBase + 32) < N_NODES ? (rowBase + 32) : N_NODES];
    int eCnt = eEndBlk - eBegBlk;

    // phase 0: stage h tiles (1 chunk/thread) + block's edge indices (coalesced)
    {
        int c8 = (t & 15) * 8;
        size_t g = (size_t)node * H_DIM + c8;
        int l = row * SSTR + c8;
        *(bf16x8*)&sHh[l] = *(const bf16x8*)(h_hi_in + g);
        *(bf16x8*)&sHl[l] = *(const bf16x8*)(h_lo + g);
    }
    {
        int lim = eCnt < EIDX_CAP ? eCnt : EIDX_CAP;
        for (int k = t; k < lim; k += 512) eIdx[k] = srcS[eBegBlk + k];
    }
    __syncthreads();

    // phase 1: gather — 16 channels (2 chunks) per thread over half the edge list.
    // R2's proven batch: 2 edges x 2 chunks = 4 independent 16B loads in flight;
    // whole next batch prefetched at one point, guarded by i+4 <= hi.
    {
        int sub   = t & 15;
        int halfI = sub >> 3;                  // which half of the edge list
        int cOff  = (sub & 7) * 16;            // 16-channel group (ushort offset)
        float a[16];
        #pragma unroll
        for (int j = 0; j < 16; ++j) a[j] = 0.f;
        if (node < N_NODES) {
            int len = end - beg;
            int h0  = (len + 1) >> 1;
            int lo  = beg + (halfI ? h0 : 0);
            int hi  = halfI ? end : beg + h0;
            const unsigned short* hb = h_hi_in + cOff;

            auto gatherRun = [&](auto IDXF) {
                int i = lo;
                int n0 = 0, n1 = 0, n2 = 0, n3 = 0;
                bool have4 = (i + 4 <= hi);
                if (have4) { n0 = IDXF(i); n1 = IDXF(i+1); n2 = IDXF(i+2); n3 = IDXF(i+3); }
                while (have4) {
                    const bf16x8* p0 = (const bf16x8*)(hb + (size_t)n0 * H_DIM);
                    const bf16x8* p1 = (const bf16x8*)(hb + (size_t)n1 * H_DIM);
                    const bf16x8* p2 = (const bf16x8*)(hb + (size_t)n2 * H_DIM);
                    const bf16x8* p3 = (const bf16x8*)(hb + (size_t)n3 * H_DIM);
                    bf16x8 v0a = p0[0], v0b = p0[1];
                    bf16x8 v1a = p1[0], v1b = p1[1];
                    bf16x8 v2a = p2[0], v2b = p2[1];
                    bf16x8 v3a = p3[0], v3b = p3[1];
                    i += 4;
                    have4 = (i + 4 <= hi);
                    if (have4) { n0 = IDXF(i); n1 = IDXF(i+1); n2 = IDXF(i+2); n3 = IDXF(i+3); }
                    #pragma unroll
                    for (int j = 0; j < 8; ++j) {
                        a[j]     += (bf2f((unsigned short)v0a[j]) + bf2f((unsigned short)v1a[j]))
                                  + (bf2f((unsigned short)v2a[j]) + bf2f((unsigned short)v3a[j]));
                        a[8 + j] += (bf2f((unsigned short)v0b[j]) + bf2f((unsigned short)v1b[j]))
                                  + (bf2f((unsigned short)v2b[j]) + bf2f((unsigned short)v3b[j]));
                    }
                }
                if (i + 2 <= hi) {
                    int q0 = IDXF(i), q1 = IDXF(i + 1);
                    const bf16x8* p0 = (const bf16x8*)(hb + (size_t)q0 * H_DIM);
                    const bf16x8* p1 = (const bf16x8*)(hb + (size_t)q1 * H_DIM);
                    bf16x8 v0a = p0[0], v0b = p0[1];
                    bf16x8 v1a = p1[0], v1b = p1[1];
                    #pragma unroll
                    for (int j = 0; j < 8; ++j) {
                        a[j]     += bf2f((unsigned short)v0a[j]) + bf2f((unsigned short)v1a[j]);
                        a[8 + j] += bf2f((unsigned short)v0b[j]) + bf2f((unsigned short)v1b[j]);
                    }
                    i += 2;
                }
                if (i < hi) {
                    int q0 = IDXF(i);
                    const bf16x8* p = (const bf16x8*)(hb + (size_t)q0 * H_DIM);
                    bf16x8 va = p[0], vb = p[1];
                    #pragma unroll
                    for (int j = 0; j < 8; ++j) {
                        a[j]     += bf2f((unsigned short)va[j]);
                        a[8 + j] += bf2f((unsigned short)vb[j]);
                    }
                }
            };

            if (eCnt <= EIDX_CAP) {
                int eb = eBegBlk;
                gatherRun([&](int x) { return eIdx[x - eb]; });
            } else {
                gatherRun([&](int x) { return srcS[x]; });
            }
        }
        // combine the two half-list partials (partner lane differs in bit 3 -> same wave)
        #pragma unroll
        for (int j = 0; j < 16; ++j) a[j] += __shfl_xor(a[j], 8);
        bf16x8 o;
        #pragma unroll
        for (int j = 0; j < 8; ++j) o[j] = (short)f2bf(a[halfI * 8 + j]);
        *(bf16x8*)&sS[row * SSTR + cOff + halfI * 8] = o;   // own slot; published by next sync
    }

    int lane = t & 63;
    int ct   = t >> 6;              // wave id = channel tile 0..7
    int rloc = lane & 15;
    int kOff = (lane >> 4) * 8;

    f32x4 accRZ[2][2], accIn[2], accHn[2];   // merged r,z; split n  (32 regs)
    #pragma unroll
    for (int rs = 0; rs < 2; ++rs) {
        accRZ[0][rs] = (f32x4){0.f, 0.f, 0.f, 0.f};
        accRZ[1][rs] = (f32x4){0.f, 0.f, 0.f, 0.f};
        accIn[rs]    = (f32x4){0.f, 0.f, 0.f, 0.f};
        accHn[rs]    = (f32x4){0.f, 0.f, 0.f, 0.f};
    }

    // phase 2: h-side MFMAs — independent of other threads' gather results
    for (int kc = 0; kc < 4; ++kc) {
        int aOff = kc * 32 + kOff;
        bf16x8 aHh4[2], aHl4[2];
        #pragma unroll
        for (int rs = 0; rs < 2; ++rs) {
            int al = (rs * 16 + rloc) * SSTR + aOff;
            aHh4[rs] = *(const bf16x8*)(&sHh[al]);
            aHl4[rs] = *(const bf16x8*)(&sHl[al]);
        }
        #pragma unroll
        for (int g = 0; g < 3; ++g) {
            size_t oH = ((size_t)((18 + g) * 32 + ct * 4 + kc) * 64 + lane) * 8;
            bf16x8 bHh = *(const bf16x8*)(PBhi + oH);
            bf16x8 bHl = *(const bf16x8*)(PBlo + oH);
            #pragma unroll
            for (int rs = 0; rs < 2; ++rs) {
                f32x4* tH = (g == 0) ? &accRZ[0][rs] : (g == 1) ? &accRZ[1][rs] : &accHn[rs];
                *tH = __builtin_amdgcn_mfma_f32_16x16x32_bf16(aHh4[rs], bHh, *tH, 0, 0, 0);
                *tH = __builtin_amdgcn_mfma_f32_16x16x32_bf16(aHl4[rs], bHh, *tH, 0, 0, 0);
                *tH = __builtin_amdgcn_mfma_f32_16x16x32_bf16(aHh4[rs], bHl, *tH, 0, 0, 0);
            }
        }
    }

    __syncthreads();    // gathered s tile complete

    // phase 3: s-side MFMAs from LDS
    const int fI0 = matI * 3;
    for (int kc = 0; kc < 4; ++kc) {
        int aOff = kc * 32 + kOff;
        bf16x8 aS[2];
        #pragma unroll
        for (int rs = 0; rs < 2; ++rs)
            aS[rs] = *(const bf16x8*)(&sS[(rs * 16 + rloc) * SSTR + aOff]);
        #pragma unroll
        for (int g = 0; g < 3; ++g) {
            size_t oI = ((size_t)((fI0 + g) * 32 + ct * 4 + kc) * 64 + lane) * 8;
            bf16x8 bIh = *(const bf16x8*)(PBhi + oI);
            bf16x8 bIl = *(const bf16x8*)(PBlo + oI);
            #pragma unroll
            for (int rs = 0; rs < 2; ++rs) {
                f32x4* tI = (g == 0) ? &accRZ[0][rs] : (g == 1) ? &accRZ[1][rs] : &accIn[rs];
                *tI = __builtin_amdgcn_mfma_f32_16x16x32_bf16(aS[rs], bIh, *tI, 0, 0, 0);
                *tI = __builtin_amdgcn_mfma_f32_16x16x32_bf16(aS[rs], bIl, *tI, 0, 0, 0);
            }
        }
    }

    // ---- epilogue: thread-local GRU for all 8 values, then single LDS round-trip ----
    int c = ct * 16 + rloc;
    float br  = b_ih[c] + b_hh[c];               // merged r bias
    float bz  = b_ih[128 + c] + b_hh[128 + c];   // merged z bias
    float bin = b_ih[256 + c], bhn = b_hh[256 + c];
    int rl = (lane >> 4) * 4;       // local row base within each 16-row subtile

    float hnv[2][4];
    #pragma unroll
    for (int rs = 0; rs < 2; ++rs) {
        #pragma unroll
        for (int r = 0; r < 4; ++r) {
            int lrow = rs * 16 + rl + r;
            float hold = bf2f(sHh[lrow * SSTR + c]) + bf2f(sHl[lrow * SSTR + c]);
            float rr = 1.f / (1.f + __expf(-(accRZ[0][rs][r] + br)));
            float zz = 1.f / (1.f + __expf(-(accRZ[1][rs][r] + bz)));
            float pre = (accIn[rs][r] + bin) + rr * (accHn[rs][r] + bhn);
            float e2 = __expf(2.f * pre);
            float cand = 1.f - 2.f / (e2 + 1.f);  // tanh, overflow-safe
            hnv[rs][r] = (1.f - zz) * cand + zz * hold;
        }
    }
    __syncthreads();                // all hold reads done; tiles now reusable
    #pragma unroll
    for (int rs = 0; rs < 2; ++rs)
        #pragma unroll
        for (int r = 0; r < 4; ++r)
            hnF[(rs * 16 + rl + r) * HSTR + c] = hnv[rs][r];   // 2-way bank alias: free
    __syncthreads();                // hn tile complete
    // coop store: 32 rows x 32 float4 chunks = 1024, 512 threads x 2
    #pragma unroll
    for (int i = t; i < 32 * 32; i += 512) {
        int rw = i >> 5;
        int c4 = (i & 31) * 4;
        int gRow = rowBase + rw;
        if (gRow < N_NODES) {
            float4 v = *(const float4*)(&hnF[rw * HSTR + c4]);
            ushort4 hh, ll;
            hh.x = f2bf(v.x); ll.x = f2bf(v.x - bf2f(hh.x));
            hh.y = f2bf(v.y); ll.y = f2bf(v.y - bf2f(hh.y));
            hh.z = f2bf(v.z); ll.z = f2bf(v.z - bf2f(hh.z));
            hh.w = f2bf(v.w); ll.w = f2bf(v.w - bf2f(hh.w));
            size_t o = (size_t)gRow * H_DIM + c4;
            *(ushort4*)(h_hi_out + o) = hh;
            *(ushort4*)(h_lo + o) = ll;
        }
    }
}

// ---------------- pool phase A: per-block segment partial sums + atomicAdd ----------------
__global__ void pool_partial(const unsigned short* __restrict__ h_hi,
                             const unsigned short* __restrict__ h_lo,
                             const int* __restrict__ batch,
                             float* __restrict__ pooled) {
    int b = blockIdx.x;             // 1563
    int t = threadIdx.x;            // 128
    int n0 = b * 64;
    if (n0 >= N_NODES) return;
    int nEnd = n0 + 64 < N_NODES ? n0 + 64 : N_NODES;
    int curG = batch[n0];
    float acc = 0.f;
    for (int n = n0; n < nEnd; ++n) {
        int g = batch[n];           // uniform across block
        if (g != curG) {            // uniform branch
            atomicAdd(&pooled[curG * H_DIM + t], acc);
            acc = 0.f;
            curG = g;
        }
        size_t o = (size_t)n * H_DIM + t;
        acc += bf2f(h_hi[o]) + bf2f(h_lo[o]);
    }
    atomicAdd(&pooled[curG * H_DIM + t], acc);
}

// ---------------- pool phase B: normalize + relu + prediction head ----------------
__global__ void pool_head(const float* __restrict__ pooled, const int* __restrict__ batch,
                          const float* __restrict__ w_pred, const float* __restrict__ b_pred,
                          float* __restrict__ out) {
    int g = blockIdx.x;             // 256 blocks
    int t = threadIdx.x;            // 128 threads
    __shared__ int bounds[2];
    __shared__ float red[2];
    if (t < 2) {
        int target = g + t;
        int lo = 0, hi = N_NODES;
        while (lo < hi) {
            int mid = (lo + hi) >> 1;
            if (batch[mid] < target) lo = mid + 1; else hi = mid;
        }
        bounds[t] = lo;
    }
    __syncthreads();
    int cnt = bounds[1] - bounds[0];
    float pv = pooled[g * H_DIM + t] / fmaxf((float)cnt, 1.f);
    pv = fmaxf(pv, 0.f);
    float v = pv * w_pred[t];
    #pragma unroll
    for (int off = 32; off > 0; off >>= 1) v += __shfl_down(v, off);
    if ((t & 63) == 0) red[t >> 6] = v;
    __syncthreads();
    if (t == 0) out[g] = red[0] + red[1] + b_pred[0];
}

extern "C" void kernel_launch(void* const* d_in, const int* in_sizes, int n_in,
                              void* d_out, int out_size, void* d_ws, size_t ws_size,
                              hipStream_t stream) {
    const float* x      = (const float*)d_in[0];
    const int*   ei     = (const int*)d_in[1];    // [2,E]: src = ei, dst = ei+E
    const int*   batch  = (const int*)d_in[2];
    const float* We     = (const float*)d_in[3];
    const float* Wm     = (const float*)d_in[4];
    const float* w_ih   = (const float*)d_in[5];
    const float* w_hh   = (const float*)d_in[6];  // [384][128] native col-major
    const float* b_ih   = (const float*)d_in[7];
    const float* b_hh   = (const float*)d_in[8];
    const float* w_pred = (const float*)d_in[9];
    const float* b_pred = (const float*)d_in[10];
    float* out = (float*)d_out;

    const size_t HN = (size_t)N_PAD * H_DIM;
    unsigned short* h_hiA = (unsigned short*)d_ws;                 // ping
    unsigned short* h_lo  = h_hiA + HN;                            // single-buffered
    unsigned short* h_hiB = h_lo + HN;                             // pong
    float* M6 = (float*)(h_hiB + HN);                              // 6*384*128 fp32
    unsigned short* PBhi = (unsigned short*)(M6 + (size_t)STEPS * TH3 * H_DIM);
    unsigned short* PBlo = PBhi + 21 * 32 * 64 * 8;
    int* offs      = (int*)(PBlo + 21 * 32 * 64 * 8);              // N+1
    int* srcSorted = offs + (N_NODES + 1);                         // E
    float* pooled  = (float*)(srcSorted + N_EDGES);                // 256*128 fp32
    // CSR temporaries overlaid on h_hiB (first written by gru step 0, after fill)
    int* count     = (int*)h_hiB;
    int* cursor    = count + N_NODES;
    int* blockSums = cursor + N_NODES;

    const int* esrc = ei;
    const int* edst = ei + N_EDGES;
    const int EB = (N_EDGES + 255) / 256;                // 6250
    const int NB = (N_NODES + 255) / 256;                // 391

    hipMemsetAsync(count, 0, 2 * (size_t)N_NODES * sizeof(int), stream);
    hipMemsetAsync(pooled, 0, (size_t)G_GRAPHS * H_DIM * sizeof(float), stream);
    hist_kernel<<<EB, 256, 0, stream>>>(edst, count);
    scan_block_kernel<<<NB, 256, 0, stream>>>(count, offs, blockSums);
    scan_sums_kernel<<<1, 512, 0, stream>>>(blockSums, NB);
    scan_add_kernel<<<NB, 256, 0, stream>>>(offs, blockSums);
    fill_kernel<<<EB, 256, 0, stream>>>(esrc, edst, offs, cursor, srcSorted);

    fuse_w_kernel<<<STEPS * (TH3 / JT), H_DIM, 0, stream>>>(Wm, w_ih, M6);
    pack_kernel<<<21 * 32, 64, 0, stream>>>(M6, w_hh, PBhi, PBlo);
    embed_kernel<<<N_NODES / ET, H_DIM, 0, stream>>>(x, We, h_hiA, h_lo);

    for (int i = 0; i < STEPS; ++i) {
        const unsigned short* hin = (i & 1) ? h_hiB : h_hiA;
        unsigned short*       hout = (i & 1) ? h_hiA : h_hiB;
        gru_fused_kernel<<<N_PAD / 32, 512, 0, stream>>>(hin, hout, h_lo,
                                                         offs, srcSorted, PBhi, PBlo,
                                                         i, b_ih, b_hh);
    }
    // STEPS=6 even -> final h lands in h_hiA

    pool_partial<<<(N_NODES + 63) / 64, H_DIM, 0, stream>>>(h_hiA, h_lo, batch, pooled);
    pool_head<<<G_GRAPHS, H_DIM, 0, stream>>>(pooled, batch, w_pred, b_pred, out);
}